// Round 13
// baseline (66.562 us; speedup 1.0000x reference)
//
#include <hip/hip_runtime.h>
#include <math.h>

// FFF sparse tree forward. B=16384, D_IN=D_OUT=768, DEPTH=11, n_nodes=4095.
//
// R10-R12 model: time ~= alpha*wave_requests + beta*bytes, alpha-dominated
// (~24 cy/request/CU). R12 halved bytes (bf16 staging) -> only -14%.
// R13 cuts REQUESTS 78 -> 54 per sample at constant bytes: each bf16 row
// (1536 B) is fetched in 2 wave-requests instead of 3:
//   req A: dwordx4, lane l -> ushort8 = dims 8l..8l+7      (dims 0-511)
//   req B: dwordx2, lane l -> ushort4 = dims 512+4l..+3    (dims 512-767)
// Lane owns 12 dims; DPP wave-sum unchanged. x / out / f64-fallback use the
// matching lane<->dim map. Routing sign exact vs f64 reference: |p| < 0.03
// -> recompute from original f32 w1s in f64 (R5-proven path).
//
// Tripwires: VGPR <= 80, WRITE_SIZE(main) == 49152 KB.

#define FFF_LVLS 12        // depth+1
#define FFF_D 768
#define FFF_ROWF4 192      // float4 per 768-f32 row
#define FFF_NODES 4095
#define WAVES_PER_BLOCK 16

typedef unsigned short u16x8 __attribute__((ext_vector_type(8)));
typedef unsigned short u16x4 __attribute__((ext_vector_type(4)));

__device__ __forceinline__ float gelu_exact(float v) {
    return 0.5f * v * (1.0f + erff(v * 0.70710678118654752440f));
}

__device__ __forceinline__ unsigned short f32_to_bf16_rne(float f) {
    unsigned int u = __builtin_bit_cast(unsigned int, f);
    u += 0x7FFFu + ((u >> 16) & 1u);
    return (unsigned short)(u >> 16);
}
__device__ __forceinline__ float bf(unsigned short h) {
    return __builtin_bit_cast(float, (unsigned int)h << 16);
}

template <int CTRL>
__device__ __forceinline__ float dpp_shr_add(float v) {
    const int t = __builtin_amdgcn_update_dpp(
        0, __builtin_bit_cast(int, v), CTRL, 0xf, 0xf, true);
    return v + __builtin_bit_cast(float, t);
}

// Wave64 sum, pure VALU; lanes 15/31/47/63 hold row totals after 4 steps.
__device__ __forceinline__ float wave_allsum_f32(float v) {
    v = dpp_shr_add<0x111>(v);   // row_shr:1
    v = dpp_shr_add<0x112>(v);   // row_shr:2
    v = dpp_shr_add<0x114>(v);   // row_shr:4
    v = dpp_shr_add<0x118>(v);   // row_shr:8
    const int i15 = __builtin_amdgcn_readlane(__builtin_bit_cast(int, v), 15);
    const int i31 = __builtin_amdgcn_readlane(__builtin_bit_cast(int, v), 31);
    const int i47 = __builtin_amdgcn_readlane(__builtin_bit_cast(int, v), 47);
    const int i63 = __builtin_amdgcn_readlane(__builtin_bit_cast(int, v), 63);
    return (__builtin_bit_cast(float, i15) + __builtin_bit_cast(float, i31))
         + (__builtin_bit_cast(float, i47) + __builtin_bit_cast(float, i63));
}

// f32 -> bf16 staging of W1 and w2 (runs each call; deterministic).
__global__ void __launch_bounds__(1024) fff_convert_kernel(
    const float4* __restrict__ w1, const float4* __restrict__ w2,
    ushort4* __restrict__ o1, ushort4* __restrict__ o2, int nf4)
{
    int i = blockIdx.x * blockDim.x + threadIdx.x;
    if (i < nf4) {
        const float4 v = w1[i];
        ushort4 h;
        h.x = f32_to_bf16_rne(v.x); h.y = f32_to_bf16_rne(v.y);
        h.z = f32_to_bf16_rne(v.z); h.w = f32_to_bf16_rne(v.w);
        o1[i] = h;
    } else if (i < 2 * nf4) {
        const int j = i - nf4;
        const float4 v = w2[j];
        ushort4 h;
        h.x = f32_to_bf16_rne(v.x); h.y = f32_to_bf16_rne(v.y);
        h.z = f32_to_bf16_rne(v.z); h.w = f32_to_bf16_rne(v.w);
        o2[j] = h;
    }
}

__global__ void __launch_bounds__(1024) fff_sparse_kernel_bf16(
    const float* __restrict__ x,
    const float* __restrict__ w1s,              // f32, sign-fallback only
    const unsigned short* __restrict__ w1b,     // bf16, 768 per row
    const unsigned short* __restrict__ w2b,
    float* __restrict__ out,
    int B)
{
    const int wave = threadIdx.x >> 6;
    const int lane = threadIdx.x & 63;
    const int b = blockIdx.x * WAVES_PER_BLOCK + wave;
    if (b >= B) return;

    const float4* __restrict__ xf4 = (const float4*)(x) + (size_t)b * FFF_ROWF4;

    // x in the packed lane<->dim map: dims 8l..8l+7 and 512+4l..+3.
    const float4 xA0 = xf4[2 * lane];
    const float4 xA1 = xf4[2 * lane + 1];
    const float4 xB  = xf4[128 + lane];

    // ---- Phase 1: tree walk on bf16 W1 (2 requests/row).
    float acts[FFF_LVLS];
    int bits = 0;
    int node = 0;

#pragma unroll
    for (int lvl = 0; lvl < FFF_LVLS; ++lvl) {
        const unsigned short* __restrict__ row = w1b + (size_t)node * FFF_D;
        const u16x8 hA = ((const u16x8*)row)[lane];          // dims 8l..8l+7
        const u16x4 hB = ((const u16x4*)(row + 512))[lane];  // dims 512+4l..

        float q0 = xA0.x * bf(hA[0]);
        float q1 = xA0.y * bf(hA[1]);
        q0 = fmaf(xA0.z, bf(hA[2]), q0);
        q1 = fmaf(xA0.w, bf(hA[3]), q1);
        q0 = fmaf(xA1.x, bf(hA[4]), q0);
        q1 = fmaf(xA1.y, bf(hA[5]), q1);
        q0 = fmaf(xA1.z, bf(hA[6]), q0);
        q1 = fmaf(xA1.w, bf(hA[7]), q1);
        q0 = fmaf(xB.x,  bf(hB[0]), q0);
        q1 = fmaf(xB.y,  bf(hB[1]), q1);
        q0 = fmaf(xB.z,  bf(hB[2]), q0);
        q1 = fmaf(xB.w,  bf(hB[3]), q1);

        float p = wave_allsum_f32(q0 + q1);   // wave-uniform

        // Sign-ambiguity fallback (|p| < 0.03, ~4% of levels): recompute
        // from ORIGINAL f32 weights in f64 so routing matches reference.
        if (__builtin_expect(fabsf(p) < 0.03f, 0)) {
            const float4* __restrict__ rf = (const float4*)w1s
                                          + (size_t)node * FFF_ROWF4;
            const float4 a0 = rf[2 * lane];
            const float4 a1 = rf[2 * lane + 1];
            const float4 a2 = rf[128 + lane];
            double d0 = (double)xA0.x * (double)a0.x;
            double d1 = (double)xA0.y * (double)a0.y;
            d0 += (double)xA0.z * (double)a0.z;
            d1 += (double)xA0.w * (double)a0.w;
            d0 += (double)xA1.x * (double)a1.x;
            d1 += (double)xA1.y * (double)a1.y;
            d0 += (double)xA1.z * (double)a1.z;
            d1 += (double)xA1.w * (double)a1.w;
            d0 += (double)xB.x  * (double)a2.x;
            d1 += (double)xB.y  * (double)a2.y;
            d0 += (double)xB.z  * (double)a2.z;
            d1 += (double)xB.w  * (double)a2.w;
            double pd = d0 + d1;
#pragma unroll
            for (int m = 32; m > 0; m >>= 1) pd += __shfl_xor(pd, m, 64);
            p = (float)pd;
        }

        acts[lvl] = gelu_exact(p);
        const int s = (p >= 0.0f) ? 1 : 0;
        bits |= s << lvl;
        node = 2 * node + 1 + s;
    }

    // ---- Phase 2: bf16 w2 accumulation (2 requests/row).
    float4 accA0 = make_float4(0.f, 0.f, 0.f, 0.f);
    float4 accA1 = make_float4(0.f, 0.f, 0.f, 0.f);
    float4 accB  = make_float4(0.f, 0.f, 0.f, 0.f);

    node = 0;
#pragma unroll
    for (int lvl = 0; lvl < FFF_LVLS; ++lvl) {
        const unsigned short* __restrict__ row = w2b + (size_t)node * FFF_D;
        const u16x8 hA = ((const u16x8*)row)[lane];
        const u16x4 hB = ((const u16x4*)(row + 512))[lane];
        const float a = acts[lvl];
        accA0.x = fmaf(a, bf(hA[0]), accA0.x);
        accA0.y = fmaf(a, bf(hA[1]), accA0.y);
        accA0.z = fmaf(a, bf(hA[2]), accA0.z);
        accA0.w = fmaf(a, bf(hA[3]), accA0.w);
        accA1.x = fmaf(a, bf(hA[4]), accA1.x);
        accA1.y = fmaf(a, bf(hA[5]), accA1.y);
        accA1.z = fmaf(a, bf(hA[6]), accA1.z);
        accA1.w = fmaf(a, bf(hA[7]), accA1.w);
        accB.x  = fmaf(a, bf(hB[0]), accB.x);
        accB.y  = fmaf(a, bf(hB[1]), accB.y);
        accB.z  = fmaf(a, bf(hB[2]), accB.z);
        accB.w  = fmaf(a, bf(hB[3]), accB.w);
        node = 2 * node + 1 + ((bits >> lvl) & 1);
    }

    float4* __restrict__ of4 = (float4*)(out) + (size_t)b * FFF_ROWF4;
    of4[2 * lane]     = accA0;
    of4[2 * lane + 1] = accA1;
    of4[128 + lane]   = accB;
}

// Fallback (ws too small): proven R11 all-f32 kernel.
__global__ void __launch_bounds__(1024) fff_sparse_kernel_f32(
    const float* __restrict__ x,
    const float* __restrict__ w1s,
    const float* __restrict__ w2s,
    float* __restrict__ out,
    int B)
{
    const int wave = threadIdx.x >> 6;
    const int lane = threadIdx.x & 63;
    const int b = blockIdx.x * WAVES_PER_BLOCK + wave;
    if (b >= B) return;

    const float4* __restrict__ xf4  = (const float4*)x;
    const float4* __restrict__ w1f4 = (const float4*)w1s;
    const float4* __restrict__ w2f4 = (const float4*)w2s;

    const int xb = b * FFF_ROWF4 + lane;
    const float4 xv0 = xf4[xb];
    const float4 xv1 = xf4[xb + 64];
    const float4 xv2 = xf4[xb + 128];

    float acts[FFF_LVLS];
    int bits = 0;
    int node = 0;

#pragma unroll
    for (int lvl = 0; lvl < FFF_LVLS; ++lvl) {
        const int r = node * FFF_ROWF4 + lane;
        const float4 a0 = w1f4[r];
        const float4 a1 = w1f4[r + 64];
        const float4 a2 = w1f4[r + 128];
        float q0 = xv0.x * a0.x;
        float q1 = xv0.y * a0.y;
        q0 = fmaf(xv0.z, a0.z, q0);
        q1 = fmaf(xv0.w, a0.w, q1);
        q0 = fmaf(xv1.x, a1.x, q0);
        q1 = fmaf(xv1.y, a1.y, q1);
        q0 = fmaf(xv1.z, a1.z, q0);
        q1 = fmaf(xv1.w, a1.w, q1);
        q0 = fmaf(xv2.x, a2.x, q0);
        q1 = fmaf(xv2.y, a2.y, q1);
        q0 = fmaf(xv2.z, a2.z, q0);
        q1 = fmaf(xv2.w, a2.w, q1);
        float p = wave_allsum_f32(q0 + q1);
        if (__builtin_expect(fabsf(p) < 1e-4f, 0)) {
            double d0 = (double)xv0.x * (double)a0.x;
            double d1 = (double)xv0.y * (double)a0.y;
            d0 += (double)xv0.z * (double)a0.z;
            d1 += (double)xv0.w * (double)a0.w;
            d0 += (double)xv1.x * (double)a1.x;
            d1 += (double)xv1.y * (double)a1.y;
            d0 += (double)xv1.z * (double)a1.z;
            d1 += (double)xv1.w * (double)a1.w;
            d0 += (double)xv2.x * (double)a2.x;
            d1 += (double)xv2.y * (double)a2.y;
            d0 += (double)xv2.z * (double)a2.z;
            d1 += (double)xv2.w * (double)a2.w;
            double pd = d0 + d1;
#pragma unroll
            for (int m = 32; m > 0; m >>= 1) pd += __shfl_xor(pd, m, 64);
            p = (float)pd;
        }
        acts[lvl] = gelu_exact(p);
        const int s = (p >= 0.0f) ? 1 : 0;
        bits |= s << lvl;
        node = 2 * node + 1 + s;
    }

    float4 acc0 = make_float4(0.f, 0.f, 0.f, 0.f);
    float4 acc1 = make_float4(0.f, 0.f, 0.f, 0.f);
    float4 acc2 = make_float4(0.f, 0.f, 0.f, 0.f);
    node = 0;
#pragma unroll
    for (int lvl = 0; lvl < FFF_LVLS; ++lvl) {
        const int r = node * FFF_ROWF4 + lane;
        const float4 c0 = w2f4[r];
        const float4 c1 = w2f4[r + 64];
        const float4 c2 = w2f4[r + 128];
        const float a = acts[lvl];
        acc0.x = fmaf(a, c0.x, acc0.x); acc0.y = fmaf(a, c0.y, acc0.y);
        acc0.z = fmaf(a, c0.z, acc0.z); acc0.w = fmaf(a, c0.w, acc0.w);
        acc1.x = fmaf(a, c1.x, acc1.x); acc1.y = fmaf(a, c1.y, acc1.y);
        acc1.z = fmaf(a, c1.z, acc1.z); acc1.w = fmaf(a, c1.w, acc1.w);
        acc2.x = fmaf(a, c2.x, acc2.x); acc2.y = fmaf(a, c2.y, acc2.y);
        acc2.z = fmaf(a, c2.z, acc2.z); acc2.w = fmaf(a, c2.w, acc2.w);
        node = 2 * node + 1 + ((bits >> lvl) & 1);
    }

    float4* __restrict__ of4 = (float4*)out;
    const int ob = b * FFF_ROWF4 + lane;
    of4[ob]       = acc0;
    of4[ob + 64]  = acc1;
    of4[ob + 128] = acc2;
}

extern "C" void kernel_launch(void* const* d_in, const int* in_sizes, int n_in,
                              void* d_out, int out_size, void* d_ws, size_t ws_size,
                              hipStream_t stream) {
    const float* x   = (const float*)d_in[0];
    const float* w1s = (const float*)d_in[1];
    const float* w2s = (const float*)d_in[2];
    float* out = (float*)d_out;

    const int B = out_size / FFF_D;                        // 16384
    const int blocks = (B + WAVES_PER_BLOCK - 1) / WAVES_PER_BLOCK;

    const size_t n_elems = (size_t)FFF_NODES * FFF_D;      // 3,144,960
    const size_t needed = 2 * n_elems * sizeof(unsigned short);

    if (ws_size >= needed) {
        unsigned short* w1b = (unsigned short*)d_ws;
        unsigned short* w2b = w1b + n_elems;
        const int nf4 = (int)(n_elems / 4);                // 786,240
        const int cblocks = (2 * nf4 + 1023) / 1024;
        fff_convert_kernel<<<cblocks, 1024, 0, stream>>>(
            (const float4*)w1s, (const float4*)w2s,
            (ushort4*)w1b, (ushort4*)w2b, nf4);
        fff_sparse_kernel_bf16<<<blocks, WAVES_PER_BLOCK * 64, 0, stream>>>(
            x, w1s, w1b, w2b, out, B);
    } else {
        fff_sparse_kernel_f32<<<blocks, WAVES_PER_BLOCK * 64, 0, stream>>>(
            x, w1s, w2s, out, B);
    }
}

// Round 14
// 66.237 us; speedup vs baseline: 1.0049x; 1.0049x over previous
//
#include <hip/hip_runtime.h>
#include <math.h>

// FFF sparse tree forward. B=16384, D_IN=D_OUT=768, DEPTH=11, n_nodes=4095.
//
// R10-R12 model: time ~= alpha*wave_requests + beta*bytes, alpha-dominated
// (~24 cy/request/CU). R12 halved bytes (bf16 staging) -> only -14%.
// R13 cuts REQUESTS 78 -> 54 per sample at constant bytes: each bf16 row
// (1536 B) is fetched in 2 wave-requests instead of 3:
//   req A: dwordx4, lane l -> ushort8 = dims 8l..8l+7      (dims 0-511)
//   req B: dwordx2, lane l -> ushort4 = dims 512+4l..+3    (dims 512-767)
// Lane owns 12 dims; DPP wave-sum unchanged. x / out / f64-fallback use the
// matching lane<->dim map. Routing sign exact vs f64 reference: |p| < 0.03
// -> recompute from original f32 w1s in f64 (R5-proven path).
//
// Tripwires: VGPR <= 80, WRITE_SIZE(main) == 49152 KB.

#define FFF_LVLS 12        // depth+1
#define FFF_D 768
#define FFF_ROWF4 192      // float4 per 768-f32 row
#define FFF_NODES 4095
#define WAVES_PER_BLOCK 16

typedef unsigned short u16x8 __attribute__((ext_vector_type(8)));
typedef unsigned short u16x4 __attribute__((ext_vector_type(4)));

__device__ __forceinline__ float gelu_exact(float v) {
    return 0.5f * v * (1.0f + erff(v * 0.70710678118654752440f));
}

__device__ __forceinline__ unsigned short f32_to_bf16_rne(float f) {
    unsigned int u = __builtin_bit_cast(unsigned int, f);
    u += 0x7FFFu + ((u >> 16) & 1u);
    return (unsigned short)(u >> 16);
}
__device__ __forceinline__ float bf(unsigned short h) {
    return __builtin_bit_cast(float, (unsigned int)h << 16);
}

template <int CTRL>
__device__ __forceinline__ float dpp_shr_add(float v) {
    const int t = __builtin_amdgcn_update_dpp(
        0, __builtin_bit_cast(int, v), CTRL, 0xf, 0xf, true);
    return v + __builtin_bit_cast(float, t);
}

// Wave64 sum, pure VALU; lanes 15/31/47/63 hold row totals after 4 steps.
__device__ __forceinline__ float wave_allsum_f32(float v) {
    v = dpp_shr_add<0x111>(v);   // row_shr:1
    v = dpp_shr_add<0x112>(v);   // row_shr:2
    v = dpp_shr_add<0x114>(v);   // row_shr:4
    v = dpp_shr_add<0x118>(v);   // row_shr:8
    const int i15 = __builtin_amdgcn_readlane(__builtin_bit_cast(int, v), 15);
    const int i31 = __builtin_amdgcn_readlane(__builtin_bit_cast(int, v), 31);
    const int i47 = __builtin_amdgcn_readlane(__builtin_bit_cast(int, v), 47);
    const int i63 = __builtin_amdgcn_readlane(__builtin_bit_cast(int, v), 63);
    return (__builtin_bit_cast(float, i15) + __builtin_bit_cast(float, i31))
         + (__builtin_bit_cast(float, i47) + __builtin_bit_cast(float, i63));
}

// f32 -> bf16 staging of W1 and w2 (runs each call; deterministic).
__global__ void __launch_bounds__(1024) fff_convert_kernel(
    const float4* __restrict__ w1, const float4* __restrict__ w2,
    ushort4* __restrict__ o1, ushort4* __restrict__ o2, int nf4)
{
    int i = blockIdx.x * blockDim.x + threadIdx.x;
    if (i < nf4) {
        const float4 v = w1[i];
        ushort4 h;
        h.x = f32_to_bf16_rne(v.x); h.y = f32_to_bf16_rne(v.y);
        h.z = f32_to_bf16_rne(v.z); h.w = f32_to_bf16_rne(v.w);
        o1[i] = h;
    } else if (i < 2 * nf4) {
        const int j = i - nf4;
        const float4 v = w2[j];
        ushort4 h;
        h.x = f32_to_bf16_rne(v.x); h.y = f32_to_bf16_rne(v.y);
        h.z = f32_to_bf16_rne(v.z); h.w = f32_to_bf16_rne(v.w);
        o2[j] = h;
    }
}

__global__ void __launch_bounds__(1024) fff_sparse_kernel_bf16(
    const float* __restrict__ x,
    const float* __restrict__ w1s,              // f32, sign-fallback only
    const unsigned short* __restrict__ w1b,     // bf16, 768 per row
    const unsigned short* __restrict__ w2b,
    float* __restrict__ out,
    int B)
{
    const int wave = threadIdx.x >> 6;
    const int lane = threadIdx.x & 63;
    const int b = blockIdx.x * WAVES_PER_BLOCK + wave;
    if (b >= B) return;

    const float4* __restrict__ xf4 = (const float4*)(x) + (size_t)b * FFF_ROWF4;

    // x in the packed lane<->dim map: dims 8l..8l+7 and 512+4l..+3.
    const float4 xA0 = xf4[2 * lane];
    const float4 xA1 = xf4[2 * lane + 1];
    const float4 xB  = xf4[128 + lane];

    // ---- Phase 1: tree walk on bf16 W1 (2 requests/row).
    float acts[FFF_LVLS];
    int bits = 0;
    int node = 0;

#pragma unroll
    for (int lvl = 0; lvl < FFF_LVLS; ++lvl) {
        const unsigned short* __restrict__ row = w1b + (size_t)node * FFF_D;
        const u16x8 hA = ((const u16x8*)row)[lane];          // dims 8l..8l+7
        const u16x4 hB = ((const u16x4*)(row + 512))[lane];  // dims 512+4l..

        float q0 = xA0.x * bf(hA[0]);
        float q1 = xA0.y * bf(hA[1]);
        q0 = fmaf(xA0.z, bf(hA[2]), q0);
        q1 = fmaf(xA0.w, bf(hA[3]), q1);
        q0 = fmaf(xA1.x, bf(hA[4]), q0);
        q1 = fmaf(xA1.y, bf(hA[5]), q1);
        q0 = fmaf(xA1.z, bf(hA[6]), q0);
        q1 = fmaf(xA1.w, bf(hA[7]), q1);
        q0 = fmaf(xB.x,  bf(hB[0]), q0);
        q1 = fmaf(xB.y,  bf(hB[1]), q1);
        q0 = fmaf(xB.z,  bf(hB[2]), q0);
        q1 = fmaf(xB.w,  bf(hB[3]), q1);

        float p = wave_allsum_f32(q0 + q1);   // wave-uniform

        // Sign-ambiguity fallback (|p| < 0.03, ~4% of levels): recompute
        // from ORIGINAL f32 weights in f64 so routing matches reference.
        if (__builtin_expect(fabsf(p) < 0.03f, 0)) {
            const float4* __restrict__ rf = (const float4*)w1s
                                          + (size_t)node * FFF_ROWF4;
            const float4 a0 = rf[2 * lane];
            const float4 a1 = rf[2 * lane + 1];
            const float4 a2 = rf[128 + lane];
            double d0 = (double)xA0.x * (double)a0.x;
            double d1 = (double)xA0.y * (double)a0.y;
            d0 += (double)xA0.z * (double)a0.z;
            d1 += (double)xA0.w * (double)a0.w;
            d0 += (double)xA1.x * (double)a1.x;
            d1 += (double)xA1.y * (double)a1.y;
            d0 += (double)xA1.z * (double)a1.z;
            d1 += (double)xA1.w * (double)a1.w;
            d0 += (double)xB.x  * (double)a2.x;
            d1 += (double)xB.y  * (double)a2.y;
            d0 += (double)xB.z  * (double)a2.z;
            d1 += (double)xB.w  * (double)a2.w;
            double pd = d0 + d1;
#pragma unroll
            for (int m = 32; m > 0; m >>= 1) pd += __shfl_xor(pd, m, 64);
            p = (float)pd;
        }

        acts[lvl] = gelu_exact(p);
        const int s = (p >= 0.0f) ? 1 : 0;
        bits |= s << lvl;
        node = 2 * node + 1 + s;
    }

    // ---- Phase 2: bf16 w2 accumulation (2 requests/row).
    float4 accA0 = make_float4(0.f, 0.f, 0.f, 0.f);
    float4 accA1 = make_float4(0.f, 0.f, 0.f, 0.f);
    float4 accB  = make_float4(0.f, 0.f, 0.f, 0.f);

    node = 0;
#pragma unroll
    for (int lvl = 0; lvl < FFF_LVLS; ++lvl) {
        const unsigned short* __restrict__ row = w2b + (size_t)node * FFF_D;
        const u16x8 hA = ((const u16x8*)row)[lane];
        const u16x4 hB = ((const u16x4*)(row + 512))[lane];
        const float a = acts[lvl];
        accA0.x = fmaf(a, bf(hA[0]), accA0.x);
        accA0.y = fmaf(a, bf(hA[1]), accA0.y);
        accA0.z = fmaf(a, bf(hA[2]), accA0.z);
        accA0.w = fmaf(a, bf(hA[3]), accA0.w);
        accA1.x = fmaf(a, bf(hA[4]), accA1.x);
        accA1.y = fmaf(a, bf(hA[5]), accA1.y);
        accA1.z = fmaf(a, bf(hA[6]), accA1.z);
        accA1.w = fmaf(a, bf(hA[7]), accA1.w);
        accB.x  = fmaf(a, bf(hB[0]), accB.x);
        accB.y  = fmaf(a, bf(hB[1]), accB.y);
        accB.z  = fmaf(a, bf(hB[2]), accB.z);
        accB.w  = fmaf(a, bf(hB[3]), accB.w);
        node = 2 * node + 1 + ((bits >> lvl) & 1);
    }

    float4* __restrict__ of4 = (float4*)(out) + (size_t)b * FFF_ROWF4;
    of4[2 * lane]     = accA0;
    of4[2 * lane + 1] = accA1;
    of4[128 + lane]   = accB;
}

// Fallback (ws too small): proven R11 all-f32 kernel.
__global__ void __launch_bounds__(1024) fff_sparse_kernel_f32(
    const float* __restrict__ x,
    const float* __restrict__ w1s,
    const float* __restrict__ w2s,
    float* __restrict__ out,
    int B)
{
    const int wave = threadIdx.x >> 6;
    const int lane = threadIdx.x & 63;
    const int b = blockIdx.x * WAVES_PER_BLOCK + wave;
    if (b >= B) return;

    const float4* __restrict__ xf4  = (const float4*)x;
    const float4* __restrict__ w1f4 = (const float4*)w1s;
    const float4* __restrict__ w2f4 = (const float4*)w2s;

    const int xb = b * FFF_ROWF4 + lane;
    const float4 xv0 = xf4[xb];
    const float4 xv1 = xf4[xb + 64];
    const float4 xv2 = xf4[xb + 128];

    float acts[FFF_LVLS];
    int bits = 0;
    int node = 0;

#pragma unroll
    for (int lvl = 0; lvl < FFF_LVLS; ++lvl) {
        const int r = node * FFF_ROWF4 + lane;
        const float4 a0 = w1f4[r];
        const float4 a1 = w1f4[r + 64];
        const float4 a2 = w1f4[r + 128];
        float q0 = xv0.x * a0.x;
        float q1 = xv0.y * a0.y;
        q0 = fmaf(xv0.z, a0.z, q0);
        q1 = fmaf(xv0.w, a0.w, q1);
        q0 = fmaf(xv1.x, a1.x, q0);
        q1 = fmaf(xv1.y, a1.y, q1);
        q0 = fmaf(xv1.z, a1.z, q0);
        q1 = fmaf(xv1.w, a1.w, q1);
        q0 = fmaf(xv2.x, a2.x, q0);
        q1 = fmaf(xv2.y, a2.y, q1);
        q0 = fmaf(xv2.z, a2.z, q0);
        q1 = fmaf(xv2.w, a2.w, q1);
        float p = wave_allsum_f32(q0 + q1);
        if (__builtin_expect(fabsf(p) < 1e-4f, 0)) {
            double d0 = (double)xv0.x * (double)a0.x;
            double d1 = (double)xv0.y * (double)a0.y;
            d0 += (double)xv0.z * (double)a0.z;
            d1 += (double)xv0.w * (double)a0.w;
            d0 += (double)xv1.x * (double)a1.x;
            d1 += (double)xv1.y * (double)a1.y;
            d0 += (double)xv1.z * (double)a1.z;
            d1 += (double)xv1.w * (double)a1.w;
            d0 += (double)xv2.x * (double)a2.x;
            d1 += (double)xv2.y * (double)a2.y;
            d0 += (double)xv2.z * (double)a2.z;
            d1 += (double)xv2.w * (double)a2.w;
            double pd = d0 + d1;
#pragma unroll
            for (int m = 32; m > 0; m >>= 1) pd += __shfl_xor(pd, m, 64);
            p = (float)pd;
        }
        acts[lvl] = gelu_exact(p);
        const int s = (p >= 0.0f) ? 1 : 0;
        bits |= s << lvl;
        node = 2 * node + 1 + s;
    }

    float4 acc0 = make_float4(0.f, 0.f, 0.f, 0.f);
    float4 acc1 = make_float4(0.f, 0.f, 0.f, 0.f);
    float4 acc2 = make_float4(0.f, 0.f, 0.f, 0.f);
    node = 0;
#pragma unroll
    for (int lvl = 0; lvl < FFF_LVLS; ++lvl) {
        const int r = node * FFF_ROWF4 + lane;
        const float4 c0 = w2f4[r];
        const float4 c1 = w2f4[r + 64];
        const float4 c2 = w2f4[r + 128];
        const float a = acts[lvl];
        acc0.x = fmaf(a, c0.x, acc0.x); acc0.y = fmaf(a, c0.y, acc0.y);
        acc0.z = fmaf(a, c0.z, acc0.z); acc0.w = fmaf(a, c0.w, acc0.w);
        acc1.x = fmaf(a, c1.x, acc1.x); acc1.y = fmaf(a, c1.y, acc1.y);
        acc1.z = fmaf(a, c1.z, acc1.z); acc1.w = fmaf(a, c1.w, acc1.w);
        acc2.x = fmaf(a, c2.x, acc2.x); acc2.y = fmaf(a, c2.y, acc2.y);
        acc2.z = fmaf(a, c2.z, acc2.z); acc2.w = fmaf(a, c2.w, acc2.w);
        node = 2 * node + 1 + ((bits >> lvl) & 1);
    }

    float4* __restrict__ of4 = (float4*)out;
    const int ob = b * FFF_ROWF4 + lane;
    of4[ob]       = acc0;
    of4[ob + 64]  = acc1;
    of4[ob + 128] = acc2;
}

extern "C" void kernel_launch(void* const* d_in, const int* in_sizes, int n_in,
                              void* d_out, int out_size, void* d_ws, size_t ws_size,
                              hipStream_t stream) {
    const float* x   = (const float*)d_in[0];
    const float* w1s = (const float*)d_in[1];
    const float* w2s = (const float*)d_in[2];
    float* out = (float*)d_out;

    const int B = out_size / FFF_D;                        // 16384
    const int blocks = (B + WAVES_PER_BLOCK - 1) / WAVES_PER_BLOCK;

    const size_t n_elems = (size_t)FFF_NODES * FFF_D;      // 3,144,960
    const size_t needed = 2 * n_elems * sizeof(unsigned short);

    if (ws_size >= needed) {
        unsigned short* w1b = (unsigned short*)d_ws;
        unsigned short* w2b = w1b + n_elems;
        const int nf4 = (int)(n_elems / 4);                // 786,240
        const int cblocks = (2 * nf4 + 1023) / 1024;
        fff_convert_kernel<<<cblocks, 1024, 0, stream>>>(
            (const float4*)w1s, (const float4*)w2s,
            (ushort4*)w1b, (ushort4*)w2b, nf4);
        fff_sparse_kernel_bf16<<<blocks, WAVES_PER_BLOCK * 64, 0, stream>>>(
            x, w1s, w1b, w2b, out, B);
    } else {
        fff_sparse_kernel_f32<<<blocks, WAVES_PER_BLOCK * 64, 0, stream>>>(
            x, w1s, w2s, out, B);
    }
}